// Round 3
// baseline (723.016 us; speedup 1.0000x reference)
//
#include <hip/hip_runtime.h>

#define B_SZ   4096
#define IN_SZ  1024
#define V_SZ   48
#define H_SZ   512
#define OUT_SZ 64

typedef __attribute__((ext_vector_type(4))) float f32x4;
typedef __attribute__((ext_vector_type(8))) short bf16x8;   // 8 bf16 in 4 VGPRs
typedef __attribute__((ext_vector_type(4))) short short4v;
typedef __attribute__((ext_vector_type(4))) float float4v;

// fp32 -> bf16 round-to-nearest-even
__device__ __forceinline__ short f2bf(float f){
    unsigned u = __builtin_bit_cast(unsigned, f);
    u += 0x7fffu + ((u >> 16) & 1u);
    return (short)(u >> 16);
}

// async global->LDS, 16B per lane; LDS dest is wave-uniform base + lane*16
__device__ __forceinline__ void gl2lds16(const void* g, void* l){
    __builtin_amdgcn_global_load_lds(
        (const __attribute__((address_space(1))) void*)g,
        (__attribute__((address_space(3))) void*)l, 16, 0, 0);
}

// ---------------- pre-pass: convert x to bf16 ----------------
__global__ void k_convert_x(const float* __restrict__ x, short* __restrict__ xb){
    int i = blockIdx.x * 256 + threadIdx.x;          // one float4 per thread
    float4v f = ((const float4v*)x)[i];
    short4v o = { f2bf(f.x), f2bf(f.y), f2bf(f.z), f2bf(f.w) };
    ((short4v*)xb)[i] = o;
}

// ---------------- pre-pass: out[v][c][r] = bf16(in[v][r][c]) ----------------
// 64x64 tiles through LDS; block (64,4)
__global__ void k_transpose_cvt(const float* __restrict__ in, short* __restrict__ out,
                                int R, int C){
    __shared__ short t[64][66];
    int v  = blockIdx.z;
    int c0 = blockIdx.x * 64, r0 = blockIdx.y * 64;
    int tx = threadIdx.x, ty = threadIdx.y;
    size_t base = (size_t)v * R * C;
    const float* inp = in + base + (size_t)r0 * C + c0;
    #pragma unroll
    for (int j = 0; j < 16; ++j){
        int r = ty + j*4;
        t[r][tx] = f2bf(inp[(size_t)r * C + tx]);
    }
    __syncthreads();
    short* outp = out + base + (size_t)c0 * R + r0;
    #pragma unroll
    for (int j = 0; j < 16; ++j){
        int cc = ty + j*4;
        outp[(size_t)cc * R + tx] = t[tx][cc];
    }
}

// ---------------- layer 1: m97-structure GEMM + bias + relu + bf16 store ----
// 256 thr (2x2 waves, 64x64/wave), BM=BN=128, BK=64, XOR-unit-swizzled LDS.
__global__ __launch_bounds__(256) void k_gemm1(
    const short* __restrict__ xb, const short* __restrict__ W1t,
    const float* __restrict__ b1, short* __restrict__ h1)
{
    __shared__ __align__(16) short As[128*64];
    __shared__ __align__(16) short Bs[128*64];
    const int tid  = threadIdx.x;
    const int lane = tid & 63, wave = tid >> 6;
    const int l15  = lane & 15, quad = lane >> 4;
    const int wm = wave & 1, wn = wave >> 1;
    const int M0 = blockIdx.x * 128;
    const int N0 = blockIdx.y * 128;
    const int v  = blockIdx.z;

    const short* a_base = xb  + (size_t)M0 * IN_SZ;
    const short* b_base = W1t + ((size_t)v * H_SZ + N0) * IN_SZ;

    const short* asrc[4]; const short* bsrc[4]; short* adst[4]; short* bdst[4];
    #pragma unroll
    for (int j = 0; j < 4; ++j){
        int p   = j*256 + tid;
        int row = p >> 3;
        int w   = (p & 7) ^ (row & 7);          // XOR swizzle on global side
        asrc[j] = a_base + (size_t)row * IN_SZ + w*8;
        bsrc[j] = b_base + (size_t)row * IN_SZ + w*8;
        adst[j] = &As[(size_t)(j*256 + (tid & ~63)) * 8];
        bdst[j] = &Bs[(size_t)(j*256 + (tid & ~63)) * 8];
    }

    f32x4 acc[4][4];
    #pragma unroll
    for (int i = 0; i < 4; ++i)
        #pragma unroll
        for (int j = 0; j < 4; ++j) acc[i][j] = (f32x4){0.f,0.f,0.f,0.f};

    for (int k0 = 0; k0 < IN_SZ; k0 += 64){
        #pragma unroll
        for (int j = 0; j < 4; ++j){
            gl2lds16(asrc[j] + k0, adst[j]);
            gl2lds16(bsrc[j] + k0, bdst[j]);
        }
        __syncthreads();
        #pragma unroll
        for (int kk = 0; kk < 2; ++kk){
            bf16x8 a[4], b[4];
            #pragma unroll
            for (int tm = 0; tm < 4; ++tm){
                int m = wm*64 + tm*16 + l15;
                int slot = m*8 + ((kk*4 + quad) ^ (m & 7));
                a[tm] = *(const bf16x8*)&As[slot*8];
            }
            #pragma unroll
            for (int tn = 0; tn < 4; ++tn){
                int n = wn*64 + tn*16 + l15;
                int slot = n*8 + ((kk*4 + quad) ^ (n & 7));
                b[tn] = *(const bf16x8*)&Bs[slot*8];
            }
            #pragma unroll
            for (int tm = 0; tm < 4; ++tm)
                #pragma unroll
                for (int tn = 0; tn < 4; ++tn)
                    acc[tm][tn] = __builtin_amdgcn_mfma_f32_16x16x32_bf16(
                        a[tm], b[tn], acc[tm][tn], 0, 0, 0);
        }
        __syncthreads();
    }

    const float* bv = b1 + (size_t)v * H_SZ;
    short* cv = h1 + (size_t)v * (B_SZ*H_SZ);
    #pragma unroll
    for (int tn = 0; tn < 4; ++tn){
        int col = N0 + wn*64 + tn*16 + l15;
        float bb = bv[col];
        #pragma unroll
        for (int tm = 0; tm < 4; ++tm){
            int rowb = M0 + wm*64 + tm*16 + quad*4;
            #pragma unroll
            for (int r = 0; r < 4; ++r){
                float val = acc[tm][tn][r] + bb;
                val = val > 0.f ? val : 0.f;
                cv[(size_t)(rowb + r) * H_SZ + col] = f2bf(val);
            }
        }
    }
}

// ---------------- layer 2, IN-PLACE: h[v][M0:M0+64][:] = relu(h @ W2[v] + b2) ----
// Full-N block (BM=64, BN=512=H, BK=64), 512 thr = 8 waves of 64x64.
// Block is the unique reader of its h1 rows -> safe to overwrite after K-loop
// (final __syncthreads drains all global_load_lds). LDS 72KB -> 2 blocks/CU.
__global__ __launch_bounds__(512) void k_gemm2_inplace(
    short* __restrict__ h, const short* __restrict__ W2t,
    const float* __restrict__ b2)
{
    __shared__ __align__(16) short As[64*64];     // 8 KB
    __shared__ __align__(16) short Bs[512*64];    // 64 KB
    const int tid  = threadIdx.x;
    const int lane = tid & 63, wave = tid >> 6;   // wave = n-slot 0..7
    const int l15  = lane & 15, quad = lane >> 4;
    const int M0 = blockIdx.x * 64;
    const int v  = blockIdx.y;

    short* hv = h + (size_t)v * (B_SZ*H_SZ) + (size_t)M0 * H_SZ;
    const short* w2v = W2t + (size_t)v * (H_SZ*H_SZ);

    // A staging: 512 units, 1/thread
    int rowA = tid >> 3;
    int wA   = (tid & 7) ^ (rowA & 7);
    const short* asrc = hv + (size_t)rowA * H_SZ + wA*8;
    short* adst = &As[(size_t)(tid & ~63) * 8];
    // B staging: 4096 units, 8/thread
    const short* bsrc[8]; short* bdst[8];
    #pragma unroll
    for (int j = 0; j < 8; ++j){
        int p   = j*512 + tid;
        int row = p >> 3;
        int w   = (p & 7) ^ (row & 7);
        bsrc[j] = w2v + (size_t)row * H_SZ + w*8;
        bdst[j] = &Bs[(size_t)(j*512 + (tid & ~63)) * 8];
    }

    f32x4 acc[4][4];
    #pragma unroll
    for (int i = 0; i < 4; ++i)
        #pragma unroll
        for (int j = 0; j < 4; ++j) acc[i][j] = (f32x4){0.f,0.f,0.f,0.f};

    for (int k0 = 0; k0 < H_SZ; k0 += 64){
        gl2lds16(asrc + k0, adst);
        #pragma unroll
        for (int j = 0; j < 8; ++j)
            gl2lds16(bsrc[j] + k0, bdst[j]);
        __syncthreads();
        #pragma unroll
        for (int kk = 0; kk < 2; ++kk){
            bf16x8 a[4], b[4];
            #pragma unroll
            for (int tm = 0; tm < 4; ++tm){
                int m = tm*16 + l15;
                int slot = m*8 + ((kk*4 + quad) ^ (m & 7));
                a[tm] = *(const bf16x8*)&As[slot*8];
            }
            #pragma unroll
            for (int tn = 0; tn < 4; ++tn){
                int n = wave*64 + tn*16 + l15;
                int slot = n*8 + ((kk*4 + quad) ^ (n & 7));
                b[tn] = *(const bf16x8*)&Bs[slot*8];
            }
            #pragma unroll
            for (int tm = 0; tm < 4; ++tm)
                #pragma unroll
                for (int tn = 0; tn < 4; ++tn)
                    acc[tm][tn] = __builtin_amdgcn_mfma_f32_16x16x32_bf16(
                        a[tm], b[tn], acc[tm][tn], 0, 0, 0);
        }
        __syncthreads();
    }

    // epilogue: overwrite own rows (in place)
    const float* bv = b2 + (size_t)v * H_SZ;
    #pragma unroll
    for (int tn = 0; tn < 4; ++tn){
        int col = wave*64 + tn*16 + l15;
        float bb = bv[col];
        #pragma unroll
        for (int tm = 0; tm < 4; ++tm){
            int rowb = tm*16 + quad*4;
            #pragma unroll
            for (int r = 0; r < 4; ++r){
                float val = acc[tm][tn][r] + bb;
                val = val > 0.f ? val : 0.f;
                hv[(size_t)(rowb + r) * H_SZ + col] = f2bf(val);
            }
        }
    }
}

// ---------------- layer 3: out[b][v*64+o] = h2[v][b][:] @ W3t[v][o][:]^T -----
// BM=128, BN=64(=OUT), BK=64; 2x2 waves of 64x32; fp32 output.
__global__ __launch_bounds__(256) void k_gemm3(
    const short* __restrict__ h2, const short* __restrict__ W3t,
    float* __restrict__ out)
{
    __shared__ __align__(16) short As[128*64];   // 16KB
    __shared__ __align__(16) short Bs[64*64];    // 8KB
    const int tid  = threadIdx.x;
    const int lane = tid & 63, wave = tid >> 6;
    const int l15  = lane & 15, quad = lane >> 4;
    const int wm = wave & 1, wn = wave >> 1;     // wave tile: 64 rows x 32 cols
    const int M0 = blockIdx.x * 128;
    const int v  = blockIdx.y;

    const short* a_base = h2  + (size_t)v * (B_SZ*H_SZ) + (size_t)M0 * H_SZ;
    const short* b_base = W3t + (size_t)v * (OUT_SZ*H_SZ);

    const short* asrc[4]; short* adst[4];
    #pragma unroll
    for (int j = 0; j < 4; ++j){
        int p = j*256 + tid;
        int row = p >> 3;
        int w   = (p & 7) ^ (row & 7);
        asrc[j] = a_base + (size_t)row * H_SZ + w*8;
        adst[j] = &As[(size_t)(j*256 + (tid & ~63)) * 8];
    }
    const short* bsrc[2]; short* bdst[2];
    #pragma unroll
    for (int j = 0; j < 2; ++j){
        int p = j*256 + tid;
        int row = p >> 3;
        int w   = (p & 7) ^ (row & 7);
        bsrc[j] = b_base + (size_t)row * H_SZ + w*8;
        bdst[j] = &Bs[(size_t)(j*256 + (tid & ~63)) * 8];
    }

    f32x4 acc[4][2];
    #pragma unroll
    for (int i = 0; i < 4; ++i)
        #pragma unroll
        for (int j = 0; j < 2; ++j) acc[i][j] = (f32x4){0.f,0.f,0.f,0.f};

    for (int k0 = 0; k0 < H_SZ; k0 += 64){
        #pragma unroll
        for (int j = 0; j < 4; ++j) gl2lds16(asrc[j] + k0, adst[j]);
        #pragma unroll
        for (int j = 0; j < 2; ++j) gl2lds16(bsrc[j] + k0, bdst[j]);
        __syncthreads();
        #pragma unroll
        for (int kk = 0; kk < 2; ++kk){
            bf16x8 a[4], b[2];
            #pragma unroll
            for (int tm = 0; tm < 4; ++tm){
                int m = wm*64 + tm*16 + l15;
                int slot = m*8 + ((kk*4 + quad) ^ (m & 7));
                a[tm] = *(const bf16x8*)&As[slot*8];
            }
            #pragma unroll
            for (int tn = 0; tn < 2; ++tn){
                int n = wn*32 + tn*16 + l15;
                int slot = n*8 + ((kk*4 + quad) ^ (n & 7));
                b[tn] = *(const bf16x8*)&Bs[slot*8];
            }
            #pragma unroll
            for (int tm = 0; tm < 4; ++tm)
                #pragma unroll
                for (int tn = 0; tn < 2; ++tn)
                    acc[tm][tn] = __builtin_amdgcn_mfma_f32_16x16x32_bf16(
                        a[tm], b[tn], acc[tm][tn], 0, 0, 0);
        }
        __syncthreads();
    }

    #pragma unroll
    for (int tn = 0; tn < 2; ++tn){
        int col = v*OUT_SZ + wn*32 + tn*16 + l15;
        #pragma unroll
        for (int tm = 0; tm < 4; ++tm){
            int rowb = M0 + wm*64 + tm*16 + quad*4;
            #pragma unroll
            for (int r = 0; r < 4; ++r)
                out[(size_t)(rowb + r) * (V_SZ*OUT_SZ) + col] = acc[tm][tn][r];
        }
    }
}

extern "C" void kernel_launch(void* const* d_in, const int* in_sizes, int n_in,
                              void* d_out, int out_size, void* d_ws, size_t ws_size,
                              hipStream_t stream)
{
    (void)in_sizes; (void)n_in; (void)out_size; (void)ws_size;
    const float* x  = (const float*)d_in[0];
    const float* W1 = (const float*)d_in[1];
    const float* b1 = (const float*)d_in[2];
    const float* W2 = (const float*)d_in[3];
    const float* b2 = (const float*)d_in[4];
    const float* W3 = (const float*)d_in[5];
    float* out = (float*)d_out;

    // workspace layout (bf16 shorts), total 275 MB — identical to round-1 footprint
    char* ws = (char*)d_ws;
    short* xb  = (short*)ws;  ws += (size_t)B_SZ * IN_SZ * 2;
    short* W1t = (short*)ws;  ws += (size_t)V_SZ * H_SZ * IN_SZ * 2;      // [v][h][i]
    short* W2t = (short*)ws;  ws += (size_t)V_SZ * H_SZ * H_SZ * 2;       // [v][n][k]
    short* W3t = (short*)ws;  ws += (size_t)V_SZ * OUT_SZ * H_SZ * 2;     // [v][o][k]
    short* h1  = (short*)ws;                                              // [v][b][h], becomes h2 in-place

    k_convert_x<<<dim3(B_SZ*IN_SZ/1024), dim3(256), 0, stream>>>(x, xb);
    k_transpose_cvt<<<dim3(H_SZ/64,  IN_SZ/64, V_SZ), dim3(64,4), 0, stream>>>(W1, W1t, IN_SZ, H_SZ);
    k_transpose_cvt<<<dim3(H_SZ/64,  H_SZ/64,  V_SZ), dim3(64,4), 0, stream>>>(W2, W2t, H_SZ, H_SZ);
    k_transpose_cvt<<<dim3(OUT_SZ/64,H_SZ/64,  V_SZ), dim3(64,4), 0, stream>>>(W3, W3t, H_SZ, OUT_SZ);

    k_gemm1<<<dim3(B_SZ/128, H_SZ/128, V_SZ), dim3(256), 0, stream>>>(xb, W1t, b1, h1);
    k_gemm2_inplace<<<dim3(B_SZ/64, V_SZ), dim3(512), 0, stream>>>(h1, W2t, b2);
    k_gemm3<<<dim3(B_SZ/128, V_SZ), dim3(256), 0, stream>>>(h1, W3t, out);
}

// Round 4
// 653.857 us; speedup vs baseline: 1.1058x; 1.1058x over previous
//
#include <hip/hip_runtime.h>

#define B_SZ   4096
#define IN_SZ  1024
#define V_SZ   48
#define H_SZ   512
#define OUT_SZ 64

typedef __attribute__((ext_vector_type(4))) float f32x4;
typedef __attribute__((ext_vector_type(8))) short bf16x8;   // 8 bf16 in 4 VGPRs
typedef __attribute__((ext_vector_type(4))) short short4v;
typedef __attribute__((ext_vector_type(4))) float float4v;

// fp32 -> bf16 round-to-nearest-even
__device__ __forceinline__ short f2bf(float f){
    unsigned u = __builtin_bit_cast(unsigned, f);
    u += 0x7fffu + ((u >> 16) & 1u);
    return (short)(u >> 16);
}

// async global->LDS, 16B per lane; LDS dest is wave-uniform base + lane*16
__device__ __forceinline__ void gl2lds16(const void* g, void* l){
    __builtin_amdgcn_global_load_lds(
        (const __attribute__((address_space(1))) void*)g,
        (__attribute__((address_space(3))) void*)l, 16, 0, 0);
}

// ---------------- pre-pass: convert x to bf16 ----------------
__global__ void k_convert_x(const float* __restrict__ x, short* __restrict__ xb){
    int i = blockIdx.x * 256 + threadIdx.x;          // one float4 per thread
    float4v f = ((const float4v*)x)[i];
    short4v o = { f2bf(f.x), f2bf(f.y), f2bf(f.z), f2bf(f.w) };
    ((short4v*)xb)[i] = o;
}

// ---------------- pre-pass: out[v][c][r] = bf16(in[v][r][c]) ----------------
// vectorized: float4 reads, b64 LDS writes, short4 global writes. 256 thr flat.
__global__ __launch_bounds__(256) void k_transpose_cvt4(
    const float* __restrict__ in, short* __restrict__ out, int R, int C)
{
    __shared__ short t[64][68];                      // 68-short stride: 8B-aligned rows
    int v  = blockIdx.z;
    int c0 = blockIdx.x * 64, r0 = blockIdx.y * 64;
    int tid = threadIdx.x;
    size_t base = (size_t)v * R * C;
    const float* inp = in + base + (size_t)r0 * C + c0;
    int g    = tid >> 4;                             // 0..15
    int col4 = (tid & 15) * 4;
    #pragma unroll
    for (int p = 0; p < 4; ++p){
        int row = p*16 + g;
        float4v f = *(const float4v*)&inp[(size_t)row * C + col4];
        short4v s = { f2bf(f.x), f2bf(f.y), f2bf(f.z), f2bf(f.w) };
        *(short4v*)&t[row][col4] = s;
    }
    __syncthreads();
    short* outp = out + base + (size_t)c0 * R + r0;
    int r4 = (tid & 15) * 4;
    #pragma unroll
    for (int p = 0; p < 4; ++p){
        int c = p*16 + g;
        short4v s = { t[r4+0][c], t[r4+1][c], t[r4+2][c], t[r4+3][c] };
        *(short4v*)&outp[(size_t)c * R + r4] = s;
    }
}

// ---------------- layer 1: m97-structure GEMM + bias + relu + bf16 store ----
// 256 thr (2x2 waves, 64x64/wave), BM=BN=128, BK=64, XOR-unit-swizzled LDS.
__global__ __launch_bounds__(256) void k_gemm1(
    const short* __restrict__ xb, const short* __restrict__ W1t,
    const float* __restrict__ b1, short* __restrict__ h1)
{
    __shared__ __align__(16) short As[128*64];
    __shared__ __align__(16) short Bs[128*64];
    const int tid  = threadIdx.x;
    const int lane = tid & 63, wave = tid >> 6;
    const int l15  = lane & 15, quad = lane >> 4;
    const int wm = wave & 1, wn = wave >> 1;
    const int M0 = blockIdx.x * 128;
    const int N0 = blockIdx.y * 128;
    const int v  = blockIdx.z;

    const short* a_base = xb  + (size_t)M0 * IN_SZ;
    const short* b_base = W1t + ((size_t)v * H_SZ + N0) * IN_SZ;

    const short* asrc[4]; const short* bsrc[4]; short* adst[4]; short* bdst[4];
    #pragma unroll
    for (int j = 0; j < 4; ++j){
        int p   = j*256 + tid;
        int row = p >> 3;
        int w   = (p & 7) ^ (row & 7);          // XOR swizzle on global side
        asrc[j] = a_base + (size_t)row * IN_SZ + w*8;
        bsrc[j] = b_base + (size_t)row * IN_SZ + w*8;
        adst[j] = &As[(size_t)(j*256 + (tid & ~63)) * 8];
        bdst[j] = &Bs[(size_t)(j*256 + (tid & ~63)) * 8];
    }

    f32x4 acc[4][4];
    #pragma unroll
    for (int i = 0; i < 4; ++i)
        #pragma unroll
        for (int j = 0; j < 4; ++j) acc[i][j] = (f32x4){0.f,0.f,0.f,0.f};

    for (int k0 = 0; k0 < IN_SZ; k0 += 64){
        #pragma unroll
        for (int j = 0; j < 4; ++j){
            gl2lds16(asrc[j] + k0, adst[j]);
            gl2lds16(bsrc[j] + k0, bdst[j]);
        }
        __syncthreads();
        #pragma unroll
        for (int kk = 0; kk < 2; ++kk){
            bf16x8 a[4], b[4];
            #pragma unroll
            for (int tm = 0; tm < 4; ++tm){
                int m = wm*64 + tm*16 + l15;
                int slot = m*8 + ((kk*4 + quad) ^ (m & 7));
                a[tm] = *(const bf16x8*)&As[slot*8];
            }
            #pragma unroll
            for (int tn = 0; tn < 4; ++tn){
                int n = wn*64 + tn*16 + l15;
                int slot = n*8 + ((kk*4 + quad) ^ (n & 7));
                b[tn] = *(const bf16x8*)&Bs[slot*8];
            }
            #pragma unroll
            for (int tm = 0; tm < 4; ++tm)
                #pragma unroll
                for (int tn = 0; tn < 4; ++tn)
                    acc[tm][tn] = __builtin_amdgcn_mfma_f32_16x16x32_bf16(
                        a[tm], b[tn], acc[tm][tn], 0, 0, 0);
        }
        __syncthreads();
    }

    const float* bv = b1 + (size_t)v * H_SZ;
    short* cv = h1 + (size_t)v * (B_SZ*H_SZ);
    #pragma unroll
    for (int tn = 0; tn < 4; ++tn){
        int col = N0 + wn*64 + tn*16 + l15;
        float bb = bv[col];
        #pragma unroll
        for (int tm = 0; tm < 4; ++tm){
            int rowb = M0 + wm*64 + tm*16 + quad*4;
            #pragma unroll
            for (int r = 0; r < 4; ++r){
                float val = acc[tm][tn][r] + bb;
                val = val > 0.f ? val : 0.f;
                cv[(size_t)(rowb + r) * H_SZ + col] = f2bf(val);
            }
        }
    }
}

// ---------------- layers 2+3 fused, full-N trick ----------------
// Phase 2: BM=64, BN=512(=H), BK=64, 512 thr = 8 waves of 64x64 (identical to
// round-3 gemm2). Epilogue: relu(h2) tile -> LDS (reuses Bs, 64KB exactly).
// Phase 3: 4 waves, K=512 from LDS, W3t B-frags from L2, fp32 -> out.
// h2 NEVER touches HBM. LDS 72KB -> 2 blocks/CU.
__global__ __launch_bounds__(512) void k_gemm23(
    const short* __restrict__ h, const short* __restrict__ W2t,
    const float* __restrict__ b2, const short* __restrict__ W3t,
    float* __restrict__ out)
{
    __shared__ __align__(16) short As[64*64];     // 8 KB
    __shared__ __align__(16) short Bs[512*64];    // 64 KB; aliased as h2s[64][512] later
    const int tid  = threadIdx.x;
    const int lane = tid & 63, wave = tid >> 6;   // wave = n-slot 0..7 in phase 2
    const int l15  = lane & 15, quad = lane >> 4;
    const int M0 = blockIdx.x * 64;
    const int v  = blockIdx.y;

    const short* hv  = h   + (size_t)v * (B_SZ*H_SZ) + (size_t)M0 * H_SZ;
    const short* w2v = W2t + (size_t)v * (H_SZ*H_SZ);
    const short* w3v = W3t + (size_t)v * (OUT_SZ*H_SZ);

    // staging: row = tid>>3 (+j*64 for B), chunk swizzle same for all j
    const int rowT = tid >> 3;
    const int wT   = (tid & 7) ^ (rowT & 7);
    const short* asrc  = hv  + (size_t)rowT * H_SZ + wT*8;
    const short* bsrc0 = w2v + (size_t)rowT * H_SZ + wT*8;
    short* adst  = &As[(size_t)(tid & ~63) * 8];
    short* bdst0 = &Bs[(size_t)(tid & ~63) * 8];

    f32x4 acc[4][4];
    #pragma unroll
    for (int i = 0; i < 4; ++i)
        #pragma unroll
        for (int j = 0; j < 4; ++j) acc[i][j] = (f32x4){0.f,0.f,0.f,0.f};

    for (int k0 = 0; k0 < H_SZ; k0 += 64){
        gl2lds16(asrc + k0, adst);
        #pragma unroll
        for (int j = 0; j < 8; ++j)
            gl2lds16(bsrc0 + (size_t)j*(64*H_SZ) + k0, bdst0 + (size_t)j*512*8);
        __syncthreads();
        #pragma unroll
        for (int kk = 0; kk < 2; ++kk){
            bf16x8 a[4], b[4];
            #pragma unroll
            for (int tm = 0; tm < 4; ++tm){
                int m = tm*16 + l15;
                int slot = m*8 + ((kk*4 + quad) ^ (m & 7));
                a[tm] = *(const bf16x8*)&As[slot*8];
            }
            #pragma unroll
            for (int tn = 0; tn < 4; ++tn){
                int n = wave*64 + tn*16 + l15;
                int slot = n*8 + ((kk*4 + quad) ^ (n & 7));
                b[tn] = *(const bf16x8*)&Bs[slot*8];
            }
            #pragma unroll
            for (int tm = 0; tm < 4; ++tm)
                #pragma unroll
                for (int tn = 0; tn < 4; ++tn)
                    acc[tm][tn] = __builtin_amdgcn_mfma_f32_16x16x32_bf16(
                        a[tm], b[tn], acc[tm][tn], 0, 0, 0);
        }
        __syncthreads();
    }

    // phase-2 epilogue: bias+relu+bf16 -> h2s in LDS (swizzled [64 rows][64 units])
    // element (row,k): Bs[row*512 + ((k>>3)^(row&7))*8 + (k&7)]
    const float* bv = b2 + (size_t)v * H_SZ;
    #pragma unroll
    for (int tn = 0; tn < 4; ++tn){
        int col = wave*64 + tn*16 + l15;
        float bb = bv[col];
        int u = col >> 3, c7 = col & 7;
        #pragma unroll
        for (int tm = 0; tm < 4; ++tm){
            int rowb = tm*16 + quad*4;
            #pragma unroll
            for (int r = 0; r < 4; ++r){
                int row = rowb + r;
                float val = acc[tm][tn][r] + bb;
                val = val > 0.f ? val : 0.f;
                Bs[row*512 + ((u ^ (row & 7))*8) + c7] = f2bf(val);
            }
        }
    }
    __syncthreads();

    // phase 3: out[M0+m][v*64+n] = h2[m][:] @ W3t[v][n][:]^T ; waves 0..3 only
    if (wave < 4){
        f32x4 acc3[4];
        #pragma unroll
        for (int i = 0; i < 4; ++i) acc3[i] = (f32x4){0.f,0.f,0.f,0.f};
        const int n3 = wave*16 + l15;
        const short* b3p = &w3v[(size_t)n3 * H_SZ + quad*8];
        #pragma unroll
        for (int kk = 0; kk < 16; ++kk){
            bf16x8 bfrag = *(const bf16x8*)&b3p[kk*32];
            int u = kk*4 + quad;
            #pragma unroll
            for (int tm = 0; tm < 4; ++tm){
                int m = tm*16 + l15;
                bf16x8 afrag = *(const bf16x8*)&Bs[m*512 + ((u ^ (m & 7))*8)];
                acc3[tm] = __builtin_amdgcn_mfma_f32_16x16x32_bf16(
                    afrag, bfrag, acc3[tm], 0, 0, 0);
            }
        }
        const int col = v*OUT_SZ + wave*16 + l15;
        #pragma unroll
        for (int tm = 0; tm < 4; ++tm){
            int rowb = M0 + tm*16 + quad*4;
            #pragma unroll
            for (int r = 0; r < 4; ++r)
                out[(size_t)(rowb + r) * (V_SZ*OUT_SZ) + col] = acc3[tm][r];
        }
    }
}

extern "C" void kernel_launch(void* const* d_in, const int* in_sizes, int n_in,
                              void* d_out, int out_size, void* d_ws, size_t ws_size,
                              hipStream_t stream)
{
    (void)in_sizes; (void)n_in; (void)out_size; (void)ws_size;
    const float* x  = (const float*)d_in[0];
    const float* W1 = (const float*)d_in[1];
    const float* b1 = (const float*)d_in[2];
    const float* W2 = (const float*)d_in[3];
    const float* b2 = (const float*)d_in[4];
    const float* W3 = (const float*)d_in[5];
    float* out = (float*)d_out;

    // workspace layout (bf16 shorts), ~288 MB — proven to fit in round 1/3
    char* ws = (char*)d_ws;
    short* xb  = (short*)ws;  ws += (size_t)B_SZ * IN_SZ * 2;
    short* W1t = (short*)ws;  ws += (size_t)V_SZ * H_SZ * IN_SZ * 2;      // [v][h][i]
    short* W2t = (short*)ws;  ws += (size_t)V_SZ * H_SZ * H_SZ * 2;       // [v][n][k]
    short* W3t = (short*)ws;  ws += (size_t)V_SZ * OUT_SZ * H_SZ * 2;     // [v][o][k]
    short* h1  = (short*)ws;                                              // [v][b][h]

    k_convert_x<<<dim3(B_SZ*IN_SZ/1024), dim3(256), 0, stream>>>(x, xb);
    k_transpose_cvt4<<<dim3(H_SZ/64,  IN_SZ/64, V_SZ), dim3(256), 0, stream>>>(W1, W1t, IN_SZ, H_SZ);
    k_transpose_cvt4<<<dim3(H_SZ/64,  H_SZ/64,  V_SZ), dim3(256), 0, stream>>>(W2, W2t, H_SZ, H_SZ);
    k_transpose_cvt4<<<dim3(OUT_SZ/64,H_SZ/64,  V_SZ), dim3(256), 0, stream>>>(W3, W3t, H_SZ, OUT_SZ);

    k_gemm1 <<<dim3(B_SZ/128, H_SZ/128, V_SZ), dim3(256), 0, stream>>>(xb, W1t, b1, h1);
    k_gemm23<<<dim3(B_SZ/64, V_SZ), dim3(512), 0, stream>>>(h1, W2t, b2, W3t, out);
}